// Round 1
// baseline (488.242 us; speedup 1.0000x reference)
//
#include <hip/hip_runtime.h>
#include <hip/hip_bf16.h>
#include <math.h>

#define DEV __device__ __forceinline__

typedef float f32x4 __attribute__((ext_vector_type(4)));
typedef short bf16x8 __attribute__((ext_vector_type(8)));

DEV unsigned short f2bf(float f) {
  union { float f; unsigned int u; } c; c.f = f;
  return (unsigned short)((c.u + 0x7FFF + ((c.u >> 16) & 1)) >> 16);
}

#define ASYNC_LD16(gp, lp)                                                     \
  __builtin_amdgcn_global_load_lds(                                            \
      (const __attribute__((address_space(1))) void*)(gp),                     \
      (__attribute__((address_space(3))) void*)(lp), 16, 0, 0)

// ---------------- weight prep kernels ----------------

// w_qkv [16][1024][192] fp32 -> wqkvt [3072][1024] bf16  (row c=h*192+f, col d)
__global__ void conv_wqkv(const float* __restrict__ in, unsigned short* __restrict__ out) {
  int i = blockIdx.x * 256 + threadIdx.x;     // over 3072*1024
  int d = i & 1023, c = i >> 10;
  int h = c / 192, f = c - h * 192;
  out[i] = f2bf(in[(long)h * 196608 + (long)d * 192 + f]);
}

// in [K][N] fp32 -> out [N][K] bf16, K = 1<<logK
__global__ void conv_t(const float* __restrict__ in, unsigned short* __restrict__ out,
                       int logK, int N) {
  long i = (long)blockIdx.x * 256 + threadIdx.x;
  int k = (int)(i & ((1 << logK) - 1));
  int n = (int)(i >> logK);
  out[i] = f2bf(in[(long)k * N + n]);
}

// W_comb[hd][e] = sum_dp w_hproj[h][d][dp] * w_out[h*64+dp][e]; store Bt: wcombt[e][hd]
__global__ void combine_wout(const float* __restrict__ w_hproj, const float* __restrict__ w_out,
                             unsigned short* __restrict__ wcombt) {
  int hd = blockIdx.x;            // 0..1023
  int h = hd >> 6, d = hd & 63;
  for (int i = 0; i < 4; i++) {
    int e = threadIdx.x + i * 256;
    float acc = 0.f;
    for (int dp = 0; dp < 64; dp++)
      acc += w_hproj[(h * 64 + d) * 64 + dp] * w_out[(h * 64 + dp) * 1024 + e];
    wcombt[(long)e * 1024 + hd] = f2bf(acc);
  }
}

// bcomb[e] = b_out[e] + sum_k b_hproj[k] * w_out[k][e]
__global__ void combine_bias(const float* __restrict__ b_hproj, const float* __restrict__ w_out,
                             const float* __restrict__ b_out, float* __restrict__ bcomb) {
  int e = blockIdx.x * 256 + threadIdx.x;
  float acc = b_out[e];
  for (int k = 0; k < 1024; k++) acc += b_hproj[k] * w_out[(long)k * 1024 + e];
  bcomb[e] = acc;
}

// ---------------- layernorm (fp32 in -> bf16 out) ----------------
__launch_bounds__(256)
__global__ void ln_kernel(const float* __restrict__ x, const float* __restrict__ g,
                          const float* __restrict__ b, unsigned short* __restrict__ out) {
  int row = blockIdx.x, t = threadIdx.x;
  float4 v = ((const float4*)(x + (long)row * 1024))[t];
  float s = v.x + v.y + v.z + v.w;
  float s2 = v.x * v.x + v.y * v.y + v.z * v.z + v.w * v.w;
  for (int o = 32; o; o >>= 1) { s += __shfl_down(s, o); s2 += __shfl_down(s2, o); }
  __shared__ float red[8];
  int w = t >> 6, l = t & 63;
  if (l == 0) { red[w] = s; red[w + 4] = s2; }
  __syncthreads();
  s = red[0] + red[1] + red[2] + red[3];
  s2 = red[4] + red[5] + red[6] + red[7];
  float mu = s * (1.f / 1024.f);
  float var = s2 * (1.f / 1024.f) - mu * mu;
  float rs = rsqrtf(var + 1e-5f);
  float4 gv = ((const float4*)g)[t];
  float4 bv = ((const float4*)b)[t];
  ushort4 o4;
  o4.x = f2bf((v.x - mu) * rs * gv.x + bv.x);
  o4.y = f2bf((v.y - mu) * rs * gv.y + bv.y);
  o4.z = f2bf((v.z - mu) * rs * gv.z + bv.z);
  o4.w = f2bf((v.w - mu) * rs * gv.w + bv.w);
  ((ushort4*)(out + (long)row * 1024))[t] = o4;
}

// ---------------- GEMM: C[M,N] = A[M,K] * Bt[N,K]^T, bf16 MFMA ----------------
#define EPI_QKV 0
#define EPI_BIASRES 1
#define EPI_GELU 2

template <int EPI>
__launch_bounds__(256)
__global__ void gemm_bt(const unsigned short* __restrict__ A, const unsigned short* __restrict__ Bt,
                        int N, int K, const float* __restrict__ bias, const float* resid,
                        float* outf, unsigned short* __restrict__ outb,
                        unsigned short* __restrict__ qb, unsigned short* __restrict__ kb,
                        unsigned short* __restrict__ vb) {
  __shared__ alignas(16) unsigned short lds_a[128 * 64];
  __shared__ alignas(16) unsigned short lds_b[128 * 64];
  int bm = blockIdx.x, bn = blockIdx.y;
  int t = threadIdx.x, w = t >> 6, l = t & 63;
  int wm = w >> 1, wn = w & 1;
  int lr = l & 15, lh = l >> 4;

  f32x4 acc[4][4];
  const f32x4 z4 = {0.f, 0.f, 0.f, 0.f};
#pragma unroll
  for (int m = 0; m < 4; m++)
#pragma unroll
    for (int n = 0; n < 4; n++) acc[m][n] = z4;

  int nk = K >> 6;
  for (int kt = 0; kt < nk; ++kt) {
    __syncthreads();
#pragma unroll
    for (int i = 0; i < 4; i++) {
      int e = i * 2048 + w * 512 + l * 8;   // element in 128x64 tile
      int row = e >> 6, col = e & 63;
      ASYNC_LD16(A + (long)(bm * 128 + row) * K + kt * 64 + col, lds_a + i * 2048 + w * 512);
      ASYNC_LD16(Bt + (long)(bn * 128 + row) * K + kt * 64 + col, lds_b + i * 2048 + w * 512);
    }
    __syncthreads();
#pragma unroll
    for (int kc = 0; kc < 2; kc++) {
      bf16x8 af[4], bfr[4];
#pragma unroll
      for (int m = 0; m < 4; m++)
        af[m] = *(const bf16x8*)&lds_a[(wm * 64 + m * 16 + lr) * 64 + kc * 32 + lh * 8];
#pragma unroll
      for (int n = 0; n < 4; n++)
        bfr[n] = *(const bf16x8*)&lds_b[(wn * 64 + n * 16 + lr) * 64 + kc * 32 + lh * 8];
#pragma unroll
      for (int m = 0; m < 4; m++)
#pragma unroll
        for (int n = 0; n < 4; n++)
          acc[m][n] = __builtin_amdgcn_mfma_f32_16x16x32_bf16(af[m], bfr[n], acc[m][n], 0, 0, 0);
    }
  }

  // epilogue: D row=(lane>>4)*4+reg, col=lane&15
#pragma unroll
  for (int m = 0; m < 4; m++) {
#pragma unroll
    for (int n = 0; n < 4; n++) {
      int c = bn * 128 + wn * 64 + n * 16 + lr;
#pragma unroll
      for (int j = 0; j < 4; j++) {
        int r = bm * 128 + wm * 64 + m * 16 + lh * 4 + j;
        float val = acc[m][n][j];
        if (EPI == EPI_QKV) {
          int h = c / 192, f = c - h * 192;
          int part = f >> 6, d = f & 63;
          int b = r >> 11, s = r & 2047;
          long idx = ((long)(b * 16 + h) * 2048 + s) * 64 + d;
          if (part == 0) qb[idx] = f2bf(val * 0.125f);
          else if (part == 1) kb[idx] = f2bf(val);
          else vb[idx] = f2bf(val);
        } else if (EPI == EPI_BIASRES) {
          long idx = (long)r * N + c;
          outf[idx] = val + bias[c] + resid[idx];
        } else {  // GELU
          float gg = val + bias[c];
          outb[(long)r * N + c] = f2bf(0.5f * gg * (1.f + erff(gg * 0.70710678118f)));
        }
      }
    }
  }
}

// ---------------- flash attention: per (b,h), 64 q-rows per block ----------------
__launch_bounds__(256)
__global__ void attn_kernel(const unsigned short* __restrict__ Qg,
                            const unsigned short* __restrict__ Kg,
                            const unsigned short* __restrict__ Vg,
                            unsigned short* __restrict__ Og) {
  __shared__ alignas(16) unsigned short k_lds[64 * 72];
  __shared__ alignas(16) unsigned short v_lds[64 * 72];   // transposed: [d][k swizzled]
  __shared__ alignas(16) unsigned short p_lds[4 * 16 * 72];
  int qt = blockIdx.x, bh = blockIdx.y;
  int t = threadIdx.x, w = t >> 6, l = t & 63, lr = l & 15, lh = l >> 4;
  const unsigned short* Qh = Qg + (long)bh * 131072;
  const unsigned short* Kh = Kg + (long)bh * 131072;
  const unsigned short* Vh = Vg + (long)bh * 131072;

  int qrow = qt * 64 + w * 16 + lr;
  bf16x8 qf0 = *(const bf16x8*)(Qh + (long)qrow * 64 + lh * 8);
  bf16x8 qf1 = *(const bf16x8*)(Qh + (long)qrow * 64 + 32 + lh * 8);

  const f32x4 z4 = {0.f, 0.f, 0.f, 0.f};
  f32x4 accO[4];
  float mrow[4], lrow[4];
#pragma unroll
  for (int j = 0; j < 4; j++) { accO[j] = z4; mrow[j] = -1e30f; lrow[j] = 0.f; }

  for (int kt = 0; kt < 32; ++kt) {
    __syncthreads();
#pragma unroll
    for (int i = 0; i < 2; i++) {
      int e = (t + i * 256) * 8;
      int row = e >> 6, col = e & 63;
      long gofs = (long)(kt * 64 + row) * 64 + col;
      *(uint4*)&k_lds[row * 72 + col] = *(const uint4*)(Kh + gofs);
      uint4 vv = *(const uint4*)(Vh + gofs);
      const unsigned short* pv = (const unsigned short*)&vv;
#pragma unroll
      for (int j = 0; j < 8; j++) {
        int d = col + j;
        int kx = row ^ ((((unsigned)d >> 3) & 7) << 3);   // swizzle k across banks
        v_lds[d * 72 + kx] = pv[j];
      }
    }
    __syncthreads();

    // S = Q K^T  (16 q-rows x 64 keys per wave)
    f32x4 sacc[4];
#pragma unroll
    for (int kbk = 0; kbk < 4; kbk++) sacc[kbk] = z4;
#pragma unroll
    for (int kbk = 0; kbk < 4; kbk++) {
      bf16x8 kf0 = *(const bf16x8*)&k_lds[(kbk * 16 + lr) * 72 + lh * 8];
      bf16x8 kf1 = *(const bf16x8*)&k_lds[(kbk * 16 + lr) * 72 + 32 + lh * 8];
      sacc[kbk] = __builtin_amdgcn_mfma_f32_16x16x32_bf16(qf0, kf0, sacc[kbk], 0, 0, 0);
      sacc[kbk] = __builtin_amdgcn_mfma_f32_16x16x32_bf16(qf1, kf1, sacc[kbk], 0, 0, 0);
    }

    // online softmax; row = lh*4+j, reduce across 16 lanes (lr)
    float fac[4];
#pragma unroll
    for (int j = 0; j < 4; j++) {
      float mx = fmaxf(fmaxf(sacc[0][j], sacc[1][j]), fmaxf(sacc[2][j], sacc[3][j]));
#pragma unroll
      for (int o = 1; o < 16; o <<= 1) mx = fmaxf(mx, __shfl_xor(mx, o));
      float mnew = fmaxf(mrow[j], mx);
      fac[j] = __expf(mrow[j] - mnew);
      mrow[j] = mnew;
      float rs = 0.f;
#pragma unroll
      for (int kbk = 0; kbk < 4; kbk++) {
        float p = __expf(sacc[kbk][j] - mnew);
        sacc[kbk][j] = p;
        rs += p;
      }
#pragma unroll
      for (int o = 1; o < 16; o <<= 1) rs += __shfl_xor(rs, o);
      lrow[j] = lrow[j] * fac[j] + rs;
    }
#pragma unroll
    for (int db = 0; db < 4; db++)
#pragma unroll
      for (int j = 0; j < 4; j++) accO[db][j] *= fac[j];

    // P -> LDS (bf16), then PV
#pragma unroll
    for (int kbk = 0; kbk < 4; kbk++)
#pragma unroll
      for (int j = 0; j < 4; j++)
        p_lds[w * 1152 + (lh * 4 + j) * 72 + kbk * 16 + lr] = f2bf(sacc[kbk][j]);
    __syncthreads();
#pragma unroll
    for (int kc = 0; kc < 2; kc++) {
      bf16x8 pf = *(const bf16x8*)&p_lds[w * 1152 + lr * 72 + kc * 32 + lh * 8];
#pragma unroll
      for (int db = 0; db < 4; db++) {
        int d = db * 16 + lr;
        bf16x8 vf = *(const bf16x8*)&v_lds[d * 72 + ((kc * 32 + lh * 8) ^ ((((unsigned)d >> 3) & 7) << 3))];
        accO[db] = __builtin_amdgcn_mfma_f32_16x16x32_bf16(pf, vf, accO[db], 0, 0, 0);
      }
    }
  }

  int b = bh >> 4, h = bh & 15;
#pragma unroll
  for (int db = 0; db < 4; db++)
#pragma unroll
    for (int j = 0; j < 4; j++) {
      int s = qt * 64 + w * 16 + lh * 4 + j;
      float val = accO[db][j] / lrow[j];
      Og[((long)(b * 2048 + s)) * 1024 + h * 64 + db * 16 + lr] = f2bf(val);
    }
}

// ---------------- launch ----------------
extern "C" void kernel_launch(void* const* d_in, const int* in_sizes, int n_in,
                              void* d_out, int out_size, void* d_ws, size_t ws_size,
                              hipStream_t stream) {
  const float* x = (const float*)d_in[0];
  const float* w_qkv = (const float*)d_in[1];
  const float* w_hproj = (const float*)d_in[2];
  const float* b_hproj = (const float*)d_in[3];
  const float* w_out = (const float*)d_in[4];
  const float* b_out = (const float*)d_in[5];
  const float* w_fc1 = (const float*)d_in[6];
  const float* b_fc1 = (const float*)d_in[7];
  const float* w_fc2 = (const float*)d_in[8];
  const float* b_fc2 = (const float*)d_in[9];
  const float* g1 = (const float*)d_in[10];
  const float* be1 = (const float*)d_in[11];
  const float* g2 = (const float*)d_in[12];
  const float* be2 = (const float*)d_in[13];
  float* out = (float*)d_out;

  char* ws = (char*)d_ws;
  unsigned short* wqkvt = (unsigned short*)(ws + 0);            // 3072*1024*2 = 6291456
  unsigned short* wfc1t = (unsigned short*)(ws + 6291456);      // 4096*1024*2 = 8388608
  unsigned short* wfc2t = (unsigned short*)(ws + 14680064);     // 8388608
  unsigned short* wcombt = (unsigned short*)(ws + 23068672);    // 2097152
  float* bcomb = (float*)(ws + 25165824);                       // 4096
  unsigned short* xn = (unsigned short*)(ws + 25169920);        // 8388608
  unsigned short* qb = (unsigned short*)(ws + 33558528);        // 8388608
  unsigned short* kb = (unsigned short*)(ws + 41947136);        // 8388608
  unsigned short* vb = (unsigned short*)(ws + 50335744);        // 8388608
  unsigned short* attn_o = (unsigned short*)(ws + 58724352);    // 8388608 -> end 67112960
  unsigned short* h1 = qb;  // alias: q/k/v/attn_o (33.5MB) free once proj GEMM done

  // weight prep
  conv_wqkv<<<12288, 256, 0, stream>>>(w_qkv, wqkvt);
  conv_t<<<16384, 256, 0, stream>>>(w_fc1, wfc1t, 10, 4096);
  conv_t<<<16384, 256, 0, stream>>>(w_fc2, wfc2t, 12, 1024);
  combine_wout<<<1024, 256, 0, stream>>>(w_hproj, w_out, wcombt);
  combine_bias<<<4, 256, 0, stream>>>(b_hproj, w_out, b_out, bcomb);

  // MSA branch
  ln_kernel<<<4096, 256, 0, stream>>>(x, g1, be1, xn);
  gemm_bt<EPI_QKV><<<dim3(32, 24), 256, 0, stream>>>(xn, wqkvt, 3072, 1024,
      nullptr, nullptr, nullptr, nullptr, qb, kb, vb);
  attn_kernel<<<dim3(32, 32), 256, 0, stream>>>(qb, kb, vb, attn_o);
  gemm_bt<EPI_BIASRES><<<dim3(32, 8), 256, 0, stream>>>(attn_o, wcombt, 1024, 1024,
      bcomb, x, out, nullptr, nullptr, nullptr, nullptr);

  // MLP branch
  ln_kernel<<<4096, 256, 0, stream>>>(out, g2, be2, xn);
  gemm_bt<EPI_GELU><<<dim3(32, 32), 256, 0, stream>>>(xn, wfc1t, 4096, 1024,
      b_fc1, nullptr, nullptr, h1, nullptr, nullptr, nullptr);
  gemm_bt<EPI_BIASRES><<<dim3(32, 8), 256, 0, stream>>>(h1, wfc2t, 1024, 4096,
      b_fc2, out, out, nullptr, nullptr, nullptr, nullptr);
}

// Round 2
// 435.565 us; speedup vs baseline: 1.1209x; 1.1209x over previous
//
#include <hip/hip_runtime.h>
#include <hip/hip_bf16.h>
#include <math.h>

#define DEV __device__ __forceinline__

typedef float f32x4 __attribute__((ext_vector_type(4)));
typedef short bf16x8 __attribute__((ext_vector_type(8)));

DEV unsigned short f2bf(float f) {
  union { float f; unsigned int u; } c; c.f = f;
  return (unsigned short)((c.u + 0x7FFF + ((c.u >> 16) & 1)) >> 16);
}

#define ASYNC_LD16(gp, lp)                                                     \
  __builtin_amdgcn_global_load_lds(                                            \
      (const __attribute__((address_space(1))) void*)(gp),                     \
      (__attribute__((address_space(3))) void*)(lp), 16, 0, 0)

// ---------------- weight prep: tiled transpose fp32 -> bf16 ----------------
// in[r][c] (R x C fp32), out[c][r] (C x R bf16). grid (C/64, R/64, batch).
__global__ void trans_f32_bf16(const float* __restrict__ in, unsigned short* __restrict__ out,
                               int R, int C, long inBatch, long outBatch) {
  __shared__ float tile[64][65];
  int ct = blockIdx.x, rt = blockIdx.y, z = blockIdx.z;
  const float* src = in + (long)z * inBatch + (long)rt * 64 * C + ct * 64;
  unsigned short* dst = out + (long)z * outBatch + (long)ct * 64 * R + rt * 64;
  int t = threadIdx.x, c = t & 63, r0 = t >> 6;
#pragma unroll
  for (int i = 0; i < 16; i++) {
    int r = i * 4 + r0;
    tile[r][c] = src[(long)r * C + c];          // coalesced read
  }
  __syncthreads();
#pragma unroll
  for (int i = 0; i < 16; i++) {
    int r = i * 4 + r0;                          // output row (= input col)
    dst[(long)r * R + c] = f2bf(tile[c][r]);     // coalesced write, 2-way-free bank read
  }
}

// W_comb[hd][e] = sum_dp w_hproj[h][d][dp] * w_out[h*64+dp][e]; store Bt: wcombt[e][hd]
__global__ void combine_wout(const float* __restrict__ w_hproj, const float* __restrict__ w_out,
                             unsigned short* __restrict__ wcombt) {
  int hd = blockIdx.x;            // 0..1023
  int h = hd >> 6, d = hd & 63;
  for (int i = 0; i < 4; i++) {
    int e = threadIdx.x + i * 256;
    float acc = 0.f;
    for (int dp = 0; dp < 64; dp++)
      acc += w_hproj[(h * 64 + d) * 64 + dp] * w_out[(h * 64 + dp) * 1024 + e];
    wcombt[(long)e * 1024 + hd] = f2bf(acc);
  }
}

// bcomb[e] = b_out[e] + sum_k b_hproj[k] * w_out[k][e]
__global__ void combine_bias(const float* __restrict__ b_hproj, const float* __restrict__ w_out,
                             const float* __restrict__ b_out, float* __restrict__ bcomb) {
  int e = blockIdx.x * 256 + threadIdx.x;
  float acc = b_out[e];
  for (int k = 0; k < 1024; k++) acc += b_hproj[k] * w_out[(long)k * 1024 + e];
  bcomb[e] = acc;
}

// V [bh][2048 s][64 d] -> Vt [bh][64 d][2048 s]. grid (32 s-tiles, 32 bh).
__global__ void transpose_v(const unsigned short* __restrict__ in, unsigned short* __restrict__ out) {
  __shared__ unsigned short tile[64][65];
  int st = blockIdx.x, bh = blockIdx.y;
  const unsigned short* src = in + (long)bh * 131072 + (long)st * 64 * 64;
  unsigned short* dst = out + (long)bh * 131072 + (long)st * 64;
  int t = threadIdx.x, c = t & 63, r0 = t >> 6;
#pragma unroll
  for (int i = 0; i < 16; i++) tile[i * 4 + r0][c] = src[(i * 4 + r0) * 64 + c];
  __syncthreads();
#pragma unroll
  for (int i = 0; i < 16; i++) {
    int d = i * 4 + r0;
    dst[(long)d * 2048 + c] = tile[c][d];
  }
}

// ---------------- layernorm (fp32 in -> bf16 out) ----------------
__launch_bounds__(256)
__global__ void ln_kernel(const float* __restrict__ x, const float* __restrict__ g,
                          const float* __restrict__ b, unsigned short* __restrict__ out) {
  int row = blockIdx.x, t = threadIdx.x;
  float4 v = ((const float4*)(x + (long)row * 1024))[t];
  float s = v.x + v.y + v.z + v.w;
  float s2 = v.x * v.x + v.y * v.y + v.z * v.z + v.w * v.w;
  for (int o = 32; o; o >>= 1) { s += __shfl_down(s, o); s2 += __shfl_down(s2, o); }
  __shared__ float red[8];
  int w = t >> 6, l = t & 63;
  if (l == 0) { red[w] = s; red[w + 4] = s2; }
  __syncthreads();
  s = red[0] + red[1] + red[2] + red[3];
  s2 = red[4] + red[5] + red[6] + red[7];
  float mu = s * (1.f / 1024.f);
  float var = s2 * (1.f / 1024.f) - mu * mu;
  float rs = rsqrtf(var + 1e-5f);
  float4 gv = ((const float4*)g)[t];
  float4 bv = ((const float4*)b)[t];
  ushort4 o4;
  o4.x = f2bf((v.x - mu) * rs * gv.x + bv.x);
  o4.y = f2bf((v.y - mu) * rs * gv.y + bv.y);
  o4.z = f2bf((v.z - mu) * rs * gv.z + bv.z);
  o4.w = f2bf((v.w - mu) * rs * gv.w + bv.w);
  ((ushort4*)(out + (long)row * 1024))[t] = o4;
}

// ---------------- GEMM: C[M,N] = A[M,K] * Bt[N,K]^T, bf16 MFMA ----------------
#define EPI_QKV 0
#define EPI_BIASRES 1
#define EPI_GELU 2

template <int EPI>
__launch_bounds__(256)
__global__ void gemm_bt(const unsigned short* __restrict__ A, const unsigned short* __restrict__ Bt,
                        int N, int K, const float* __restrict__ bias, const float* resid,
                        float* outf, unsigned short* __restrict__ outb,
                        unsigned short* __restrict__ qb, unsigned short* __restrict__ kb,
                        unsigned short* __restrict__ vb) {
  __shared__ alignas(16) unsigned short lds_a[128 * 64];
  __shared__ alignas(16) unsigned short lds_b[128 * 64];
  // XCD-aware swizzle (all grids here have nwg % 8 == 0): each XCD gets a
  // contiguous tile range -> shared B-panels stay in its private L2.
  int gx = gridDim.x, nwg = gx * gridDim.y;
  int orig = blockIdx.y * gx + blockIdx.x;
  int cpx = nwg >> 3;
  int wg = (orig & 7) * cpx + (orig >> 3);
  int bm = wg % gx, bn = wg / gx;

  int t = threadIdx.x, w = t >> 6, l = t & 63;
  int wm = w >> 1, wn = w & 1;
  int lr = l & 15, lh = l >> 4;

  f32x4 acc[4][4];
  const f32x4 z4 = {0.f, 0.f, 0.f, 0.f};
#pragma unroll
  for (int m = 0; m < 4; m++)
#pragma unroll
    for (int n = 0; n < 4; n++) acc[m][n] = z4;

  int nk = K >> 6;
  for (int kt = 0; kt < nk; ++kt) {
    __syncthreads();
#pragma unroll
    for (int i = 0; i < 4; i++) {
      int e = i * 2048 + w * 512 + l * 8;   // element in 128x64 tile
      int row = e >> 6, col = e & 63;
      ASYNC_LD16(A + (long)(bm * 128 + row) * K + kt * 64 + col, lds_a + i * 2048 + w * 512);
      ASYNC_LD16(Bt + (long)(bn * 128 + row) * K + kt * 64 + col, lds_b + i * 2048 + w * 512);
    }
    __syncthreads();
#pragma unroll
    for (int kc = 0; kc < 2; kc++) {
      bf16x8 af[4], bfr[4];
#pragma unroll
      for (int m = 0; m < 4; m++)
        af[m] = *(const bf16x8*)&lds_a[(wm * 64 + m * 16 + lr) * 64 + kc * 32 + lh * 8];
#pragma unroll
      for (int n = 0; n < 4; n++)
        bfr[n] = *(const bf16x8*)&lds_b[(wn * 64 + n * 16 + lr) * 64 + kc * 32 + lh * 8];
      __builtin_amdgcn_s_setprio(1);
#pragma unroll
      for (int m = 0; m < 4; m++)
#pragma unroll
        for (int n = 0; n < 4; n++)
          acc[m][n] = __builtin_amdgcn_mfma_f32_16x16x32_bf16(af[m], bfr[n], acc[m][n], 0, 0, 0);
      __builtin_amdgcn_s_setprio(0);
    }
  }

  // epilogue: D row=(lane>>4)*4+reg, col=lane&15
#pragma unroll
  for (int m = 0; m < 4; m++) {
#pragma unroll
    for (int n = 0; n < 4; n++) {
      int c = bn * 128 + wn * 64 + n * 16 + lr;
#pragma unroll
      for (int j = 0; j < 4; j++) {
        int r = bm * 128 + wm * 64 + m * 16 + lh * 4 + j;
        float val = acc[m][n][j];
        if (EPI == EPI_QKV) {
          int h = c / 192, f = c - h * 192;
          int part = f >> 6, d = f & 63;
          int b = r >> 11, s = r & 2047;
          long idx = ((long)(b * 16 + h) * 2048 + s) * 64 + d;
          if (part == 0) qb[idx] = f2bf(val * 0.125f);
          else if (part == 1) kb[idx] = f2bf(val);
          else vb[idx] = f2bf(val);
        } else if (EPI == EPI_BIASRES) {
          long idx = (long)r * N + c;
          outf[idx] = val + bias[c] + resid[idx];
        } else {  // GELU
          float gg = val + bias[c];
          outb[(long)r * N + c] = f2bf(0.5f * gg * (1.f + erff(gg * 0.70710678118f)));
        }
      }
    }
  }
}

// ---------------- flash attention ----------------
// Per (b,h): 64 q-rows per block, 4 waves x 16 q-rows. K and Vt staged via
// global_load_lds with XOR-swizzled source (linear LDS dest), swizzled reads.
__launch_bounds__(256)
__global__ void attn_kernel(const unsigned short* __restrict__ Qg,
                            const unsigned short* __restrict__ Kg,
                            const unsigned short* __restrict__ Vt,
                            unsigned short* __restrict__ Og) {
  __shared__ alignas(16) unsigned short k_lds[64 * 64];   // [key][d], content swizzled
  __shared__ alignas(16) unsigned short v_lds[64 * 64];   // [d][key], content swizzled
  __shared__ alignas(16) unsigned short p_lds[4 * 16 * 72];
  // XCD swizzle: grid (32 qt, 32 bh), 1024 blocks -> each XCD owns 4 whole bh
  // (K/V = 512 KB per bh stays L2-resident per XCD).
  int orig = blockIdx.y * 32 + blockIdx.x;
  int wg = (orig & 7) * 128 + (orig >> 3);
  int qt = wg & 31, bh = wg >> 5;

  int t = threadIdx.x, w = t >> 6, l = t & 63, lr = l & 15, lh = l >> 4;
  const unsigned short* Qh = Qg + (long)bh * 131072;
  const char* Kh = (const char*)(Kg + (long)bh * 131072);
  const char* Vh = (const char*)(Vt + (long)bh * 131072);

  int qrow = qt * 64 + w * 16 + lr;
  bf16x8 qf0 = *(const bf16x8*)(Qh + (long)qrow * 64 + lh * 8);
  bf16x8 qf1 = *(const bf16x8*)(Qh + (long)qrow * 64 + 32 + lh * 8);

  const f32x4 z4 = {0.f, 0.f, 0.f, 0.f};
  f32x4 accO[4];
  float mrow[4], lrow[4];
#pragma unroll
  for (int j = 0; j < 4; j++) { accO[j] = z4; mrow[j] = -1e30f; lrow[j] = 0.f; }

  for (int kt = 0; kt < 32; ++kt) {
    __syncthreads();
    // stage K tile [64 keys][64 d] and Vt tile [64 d][64 keys], 8 KB each.
    // LDS dest is linear (base + lane*16); global source column pre-swizzled
    // by XOR((row&7)<<4) within each 128B row so reads can XOR the same way.
#pragma unroll
    for (int i = 0; i < 2; i++) {
      int o = (t + i * 256) * 16;               // byte offset in 8 KB tile
      int row = o >> 7;
      int colb = (o & 127) ^ ((row & 7) << 4);
      ASYNC_LD16(Kh + (long)(kt * 64 + row) * 128 + colb,
                 (char*)k_lds + (w * 64 + i * 256) * 16);
      ASYNC_LD16(Vh + (long)row * 4096 + kt * 128 + colb,
                 (char*)v_lds + (w * 64 + i * 256) * 16);
    }
    __syncthreads();

    // S = Q K^T  (16 q-rows x 64 keys per wave)
    f32x4 sacc[4];
#pragma unroll
    for (int kbk = 0; kbk < 4; kbk++) sacc[kbk] = z4;
    __builtin_amdgcn_s_setprio(1);
#pragma unroll
    for (int kbk = 0; kbk < 4; kbk++) {
      int krow = kbk * 16 + lr;
      int sw = (krow & 7) << 4;
      bf16x8 kf0 = *(const bf16x8*)((const char*)k_lds + krow * 128 + ((lh * 16) ^ sw));
      bf16x8 kf1 = *(const bf16x8*)((const char*)k_lds + krow * 128 + ((64 + lh * 16) ^ sw));
      sacc[kbk] = __builtin_amdgcn_mfma_f32_16x16x32_bf16(qf0, kf0, sacc[kbk], 0, 0, 0);
      sacc[kbk] = __builtin_amdgcn_mfma_f32_16x16x32_bf16(qf1, kf1, sacc[kbk], 0, 0, 0);
    }
    __builtin_amdgcn_s_setprio(0);

    // online softmax; row = lh*4+j, reduce across 16 lanes (lr)
    float fac[4];
#pragma unroll
    for (int j = 0; j < 4; j++) {
      float mx = fmaxf(fmaxf(sacc[0][j], sacc[1][j]), fmaxf(sacc[2][j], sacc[3][j]));
#pragma unroll
      for (int o = 1; o < 16; o <<= 1) mx = fmaxf(mx, __shfl_xor(mx, o));
      float mnew = fmaxf(mrow[j], mx);
      fac[j] = __expf(mrow[j] - mnew);
      mrow[j] = mnew;
      float rs = 0.f;
#pragma unroll
      for (int kbk = 0; kbk < 4; kbk++) {
        float p = __expf(sacc[kbk][j] - mnew);
        sacc[kbk][j] = p;
        rs += p;
      }
#pragma unroll
      for (int o = 1; o < 16; o <<= 1) rs += __shfl_xor(rs, o);
      lrow[j] = lrow[j] * fac[j] + rs;
    }
#pragma unroll
    for (int db = 0; db < 4; db++)
#pragma unroll
      for (int j = 0; j < 4; j++) accO[db][j] *= fac[j];

    // P -> LDS (bf16), then PV
#pragma unroll
    for (int kbk = 0; kbk < 4; kbk++)
#pragma unroll
      for (int j = 0; j < 4; j++)
        p_lds[w * 1152 + (lh * 4 + j) * 72 + kbk * 16 + lr] = f2bf(sacc[kbk][j]);
    __syncthreads();
    __builtin_amdgcn_s_setprio(1);
#pragma unroll
    for (int kc = 0; kc < 2; kc++) {
      bf16x8 pf = *(const bf16x8*)&p_lds[w * 1152 + lr * 72 + kc * 32 + lh * 8];
#pragma unroll
      for (int db = 0; db < 4; db++) {
        int d = db * 16 + lr;
        int sw = (d & 7) << 4;
        bf16x8 vf = *(const bf16x8*)((const char*)v_lds + d * 128 + ((kc * 64 + lh * 16) ^ sw));
        accO[db] = __builtin_amdgcn_mfma_f32_16x16x32_bf16(pf, vf, accO[db], 0, 0, 0);
      }
    }
    __builtin_amdgcn_s_setprio(0);
  }

  int b = bh >> 4, h = bh & 15;
#pragma unroll
  for (int db = 0; db < 4; db++)
#pragma unroll
    for (int j = 0; j < 4; j++) {
      int s = qt * 64 + w * 16 + lh * 4 + j;
      float val = accO[db][j] / lrow[j];
      Og[((long)(b * 2048 + s)) * 1024 + h * 64 + db * 16 + lr] = f2bf(val);
    }
}

// ---------------- launch ----------------
extern "C" void kernel_launch(void* const* d_in, const int* in_sizes, int n_in,
                              void* d_out, int out_size, void* d_ws, size_t ws_size,
                              hipStream_t stream) {
  const float* x = (const float*)d_in[0];
  const float* w_qkv = (const float*)d_in[1];
  const float* w_hproj = (const float*)d_in[2];
  const float* b_hproj = (const float*)d_in[3];
  const float* w_out = (const float*)d_in[4];
  const float* b_out = (const float*)d_in[5];
  const float* w_fc1 = (const float*)d_in[6];
  const float* b_fc1 = (const float*)d_in[7];
  const float* w_fc2 = (const float*)d_in[8];
  const float* b_fc2 = (const float*)d_in[9];
  const float* g1 = (const float*)d_in[10];
  const float* be1 = (const float*)d_in[11];
  const float* g2 = (const float*)d_in[12];
  const float* be2 = (const float*)d_in[13];
  float* out = (float*)d_out;

  char* ws = (char*)d_ws;
  unsigned short* wqkvt = (unsigned short*)(ws + 0);            // 3072*1024*2 = 6291456
  unsigned short* wfc1t = (unsigned short*)(ws + 6291456);      // 4096*1024*2 = 8388608
  unsigned short* wfc2t = (unsigned short*)(ws + 14680064);     // 8388608
  unsigned short* wcombt = (unsigned short*)(ws + 23068672);    // 2097152
  float* bcomb = (float*)(ws + 25165824);                       // 4096
  unsigned short* xn = (unsigned short*)(ws + 25169920);        // 8388608
  unsigned short* qb = (unsigned short*)(ws + 33558528);        // 8388608
  unsigned short* kb = (unsigned short*)(ws + 41947136);        // 8388608
  unsigned short* vb = (unsigned short*)(ws + 50335744);        // 8388608
  unsigned short* attn_o = (unsigned short*)(ws + 58724352);    // 8388608 -> end 67112960
  unsigned short* h1 = qb;   // alias: q/k/v free once attention is done
  unsigned short* vt = xn;   // alias: xn (LN1 out) is dead once QKV GEMM ran

  // weight prep (all coalesced tiled transposes now)
  // w_qkv [16 h][1024 d][192 f] -> wqkvt[h*192+f][d]: per-head transpose
  trans_f32_bf16<<<dim3(3, 16, 16), 256, 0, stream>>>(w_qkv, wqkvt, 1024, 192,
                                                      196608L, 196608L);
  // w_fc1 [1024][4096] -> wfc1t [4096][1024]
  trans_f32_bf16<<<dim3(64, 16, 1), 256, 0, stream>>>(w_fc1, wfc1t, 1024, 4096, 0, 0);
  // w_fc2 [4096][1024] -> wfc2t [1024][4096]
  trans_f32_bf16<<<dim3(16, 64, 1), 256, 0, stream>>>(w_fc2, wfc2t, 4096, 1024, 0, 0);
  combine_wout<<<1024, 256, 0, stream>>>(w_hproj, w_out, wcombt);
  combine_bias<<<4, 256, 0, stream>>>(b_hproj, w_out, b_out, bcomb);

  // MSA branch
  ln_kernel<<<4096, 256, 0, stream>>>(x, g1, be1, xn);
  gemm_bt<EPI_QKV><<<dim3(32, 24), 256, 0, stream>>>(xn, wqkvt, 3072, 1024,
      nullptr, nullptr, nullptr, nullptr, qb, kb, vb);
  transpose_v<<<dim3(32, 32), 256, 0, stream>>>(vb, vt);
  attn_kernel<<<dim3(32, 32), 256, 0, stream>>>(qb, kb, vt, attn_o);
  gemm_bt<EPI_BIASRES><<<dim3(32, 8), 256, 0, stream>>>(attn_o, wcombt, 1024, 1024,
      bcomb, x, out, nullptr, nullptr, nullptr, nullptr);

  // MLP branch
  ln_kernel<<<4096, 256, 0, stream>>>(out, g2, be2, xn);
  gemm_bt<EPI_GELU><<<dim3(32, 32), 256, 0, stream>>>(xn, wfc1t, 4096, 1024,
      b_fc1, nullptr, nullptr, h1, nullptr, nullptr, nullptr);
  gemm_bt<EPI_BIASRES><<<dim3(32, 8), 256, 0, stream>>>(h1, wfc2t, 1024, 4096,
      b_fc2, out, out, nullptr, nullptr, nullptr, nullptr);
}

// Round 3
// 378.222 us; speedup vs baseline: 1.2909x; 1.1516x over previous
//
#include <hip/hip_runtime.h>
#include <hip/hip_bf16.h>
#include <math.h>

#define DEV __device__ __forceinline__

typedef float f32x4 __attribute__((ext_vector_type(4)));
typedef short bf16x8 __attribute__((ext_vector_type(8)));

DEV unsigned short f2bf(float f) {
  union { float f; unsigned int u; } c; c.f = f;
  return (unsigned short)((c.u + 0x7FFF + ((c.u >> 16) & 1)) >> 16);
}

#define ASYNC_LD16(gp, lp)                                                     \
  __builtin_amdgcn_global_load_lds(                                            \
      (const __attribute__((address_space(1))) void*)(gp),                     \
      (__attribute__((address_space(3))) void*)(lp), 16, 0, 0)

// ---------------- weight prep: tiled transpose fp32 -> bf16 ----------------
__global__ void trans_f32_bf16(const float* __restrict__ in, unsigned short* __restrict__ out,
                               int R, int C, long inBatch, long outBatch) {
  __shared__ float tile[64][65];
  int ct = blockIdx.x, rt = blockIdx.y, z = blockIdx.z;
  const float* src = in + (long)z * inBatch + (long)rt * 64 * C + ct * 64;
  unsigned short* dst = out + (long)z * outBatch + (long)ct * 64 * R + rt * 64;
  int t = threadIdx.x, c = t & 63, r0 = t >> 6;
#pragma unroll
  for (int i = 0; i < 16; i++) {
    int r = i * 4 + r0;
    tile[r][c] = src[(long)r * C + c];
  }
  __syncthreads();
#pragma unroll
  for (int i = 0; i < 16; i++) {
    int r = i * 4 + r0;
    dst[(long)r * R + c] = f2bf(tile[c][r]);
  }
}

// W_comb[hd][e] = sum_dp w_hproj[h][d][dp] * w_out[h*64+dp][e]; store Bt
__global__ void combine_wout(const float* __restrict__ w_hproj, const float* __restrict__ w_out,
                             unsigned short* __restrict__ wcombt) {
  int hd = blockIdx.x;
  int h = hd >> 6, d = hd & 63;
  for (int i = 0; i < 4; i++) {
    int e = threadIdx.x + i * 256;
    float acc = 0.f;
    for (int dp = 0; dp < 64; dp++)
      acc += w_hproj[(h * 64 + d) * 64 + dp] * w_out[(h * 64 + dp) * 1024 + e];
    wcombt[(long)e * 1024 + hd] = f2bf(acc);
  }
}

// bcomb[e] = b_out[e] + sum_k b_hproj[k] * w_out[k][e].  grid 32 x 256.
__global__ void combine_bias(const float* __restrict__ b_hproj, const float* __restrict__ w_out,
                             const float* __restrict__ b_out, float* __restrict__ bcomb) {
  __shared__ float part[8][32];
  int e = blockIdx.x * 32 + (threadIdx.x & 31);
  int ks = threadIdx.x >> 5;
  float acc = 0.f;
  for (int k = ks * 128; k < ks * 128 + 128; k++) acc += b_hproj[k] * w_out[(long)k * 1024 + e];
  part[ks][threadIdx.x & 31] = acc;
  __syncthreads();
  if (threadIdx.x < 32) {
    float s = b_out[e];
#pragma unroll
    for (int i = 0; i < 8; i++) s += part[i][threadIdx.x];
    bcomb[e] = s;
  }
}

// V [bh][2048 s][64 d] -> Vt [bh][64 d][2048 s], with key order inside each
// 64-key tile permuted to match the PV MFMA A-fragment slot layout:
// slot p holds key kappa(p) = (2g+sub)*16 + hi*4 + jj  where
// p = g*32 + hi*8 + sub*4 + jj.  (So P needs ZERO cross-lane movement.)
__global__ void transpose_v(const unsigned short* __restrict__ in, unsigned short* __restrict__ out) {
  __shared__ unsigned short tile[64][65];
  int st = blockIdx.x, bh = blockIdx.y;
  const unsigned short* src = in + (long)bh * 131072 + (long)st * 64 * 64;
  unsigned short* dst = out + (long)bh * 131072 + (long)st * 64;
  int t = threadIdx.x, c = t & 63, r0 = t >> 6;
#pragma unroll
  for (int i = 0; i < 16; i++) tile[i * 4 + r0][c] = src[(i * 4 + r0) * 64 + c];
  __syncthreads();
  // position of key c within the 64-tile
  int kb = c >> 4, g = kb >> 1, sub = kb & 1, hi2 = (c >> 2) & 3, jj = c & 3;
  int pos = g * 32 + hi2 * 8 + sub * 4 + jj;
#pragma unroll
  for (int i = 0; i < 16; i++) {
    int d = i * 4 + r0;
    dst[(long)d * 2048 + pos] = tile[c][d];
  }
}

// ---------------- layernorm (fp32 in -> bf16 out) ----------------
__launch_bounds__(256)
__global__ void ln_kernel(const float* __restrict__ x, const float* __restrict__ g,
                          const float* __restrict__ b, unsigned short* __restrict__ out) {
  int row = blockIdx.x, t = threadIdx.x;
  float4 v = ((const float4*)(x + (long)row * 1024))[t];
  float s = v.x + v.y + v.z + v.w;
  float s2 = v.x * v.x + v.y * v.y + v.z * v.z + v.w * v.w;
  for (int o = 32; o; o >>= 1) { s += __shfl_down(s, o); s2 += __shfl_down(s2, o); }
  __shared__ float red[8];
  int w = t >> 6, l = t & 63;
  if (l == 0) { red[w] = s; red[w + 4] = s2; }
  __syncthreads();
  s = red[0] + red[1] + red[2] + red[3];
  s2 = red[4] + red[5] + red[6] + red[7];
  float mu = s * (1.f / 1024.f);
  float var = s2 * (1.f / 1024.f) - mu * mu;
  float rs = rsqrtf(var + 1e-5f);
  float4 gv = ((const float4*)g)[t];
  float4 bv = ((const float4*)b)[t];
  ushort4 o4;
  o4.x = f2bf((v.x - mu) * rs * gv.x + bv.x);
  o4.y = f2bf((v.y - mu) * rs * gv.y + bv.y);
  o4.z = f2bf((v.z - mu) * rs * gv.z + bv.z);
  o4.w = f2bf((v.w - mu) * rs * gv.w + bv.w);
  ((ushort4*)(out + (long)row * 1024))[t] = o4;
}

// ---------------- GEMM: C[M,N] = A[M,K] * Bt[N,K]^T, bf16 MFMA ----------------
#define EPI_QKV 0
#define EPI_BIASRES 1
#define EPI_GELU 2

template <int EPI>
__launch_bounds__(256)
__global__ void gemm_bt(const unsigned short* __restrict__ A, const unsigned short* __restrict__ Bt,
                        int N, int K, const float* __restrict__ bias, const float* resid,
                        float* outf, unsigned short* __restrict__ outb,
                        unsigned short* __restrict__ qb, unsigned short* __restrict__ kb,
                        unsigned short* __restrict__ vb) {
  __shared__ alignas(16) unsigned short lds_a[128 * 64];
  __shared__ alignas(16) unsigned short lds_b[128 * 64];
  int gx = gridDim.x, nwg = gx * gridDim.y;
  int orig = blockIdx.y * gx + blockIdx.x;
  int cpx = nwg >> 3;
  int wg = (orig & 7) * cpx + (orig >> 3);
  int bm = wg % gx, bn = wg / gx;

  int t = threadIdx.x, w = t >> 6, l = t & 63;
  int wm = w >> 1, wn = w & 1;
  int lr = l & 15, lh = l >> 4;

  f32x4 acc[4][4];
  const f32x4 z4 = {0.f, 0.f, 0.f, 0.f};
#pragma unroll
  for (int m = 0; m < 4; m++)
#pragma unroll
    for (int n = 0; n < 4; n++) acc[m][n] = z4;

  int nk = K >> 6;
  for (int kt = 0; kt < nk; ++kt) {
    __syncthreads();
#pragma unroll
    for (int i = 0; i < 4; i++) {
      int e = i * 2048 + w * 512 + l * 8;
      int row = e >> 6, col = e & 63;
      ASYNC_LD16(A + (long)(bm * 128 + row) * K + kt * 64 + col, lds_a + i * 2048 + w * 512);
      ASYNC_LD16(Bt + (long)(bn * 128 + row) * K + kt * 64 + col, lds_b + i * 2048 + w * 512);
    }
    __syncthreads();
#pragma unroll
    for (int kc = 0; kc < 2; kc++) {
      bf16x8 af[4], bfr[4];
#pragma unroll
      for (int m = 0; m < 4; m++)
        af[m] = *(const bf16x8*)&lds_a[(wm * 64 + m * 16 + lr) * 64 + kc * 32 + lh * 8];
#pragma unroll
      for (int n = 0; n < 4; n++)
        bfr[n] = *(const bf16x8*)&lds_b[(wn * 64 + n * 16 + lr) * 64 + kc * 32 + lh * 8];
      __builtin_amdgcn_s_setprio(1);
#pragma unroll
      for (int m = 0; m < 4; m++)
#pragma unroll
        for (int n = 0; n < 4; n++)
          acc[m][n] = __builtin_amdgcn_mfma_f32_16x16x32_bf16(af[m], bfr[n], acc[m][n], 0, 0, 0);
      __builtin_amdgcn_s_setprio(0);
    }
  }

#pragma unroll
  for (int m = 0; m < 4; m++) {
#pragma unroll
    for (int n = 0; n < 4; n++) {
      int c = bn * 128 + wn * 64 + n * 16 + lr;
#pragma unroll
      for (int j = 0; j < 4; j++) {
        int r = bm * 128 + wm * 64 + m * 16 + lh * 4 + j;
        float val = acc[m][n][j];
        if (EPI == EPI_QKV) {
          int h = c / 192, f = c - h * 192;
          int part = f >> 6, d = f & 63;
          int b = r >> 11, s = r & 2047;
          long idx = ((long)(b * 16 + h) * 2048 + s) * 64 + d;
          // q pre-scaled by 1/8 * log2(e) so attention softmax runs in exp2 domain
          if (part == 0) qb[idx] = f2bf(val * 0.18033688011112042f);
          else if (part == 1) kb[idx] = f2bf(val);
          else vb[idx] = f2bf(val);
        } else if (EPI == EPI_BIASRES) {
          long idx = (long)r * N + c;
          outf[idx] = val + bias[c] + resid[idx];
        } else {  // GELU (tanh form; |err| ~3e-3 << 0.1175 threshold, under bf16 quant)
          float u = val + bias[c];
          float z2 = u * (0.7978845608f + 0.0356774081f * u * u) * 2.885390082f;
          float e2 = exp2f(z2);
          float th = 1.f - 2.f / (e2 + 1.f);
          outb[(long)r * N + c] = f2bf(0.5f * u * (1.f + th));
        }
      }
    }
  }
}

// ---------------- flash attention, in-register softmax ----------------
// Swapped QK^T: sacc = mfma(K_frag, Q_frag) -> S^T, lane owns q=lane&15,
// keys kappa = kbk*16 + hi*4 + reg (hi = lane>>4). Row softmax: 15 in-lane
// fmax + 2 shfl_xor. P feeds PV A-frag directly (V pre-permuted in global).
__launch_bounds__(256)
__global__ void attn_kernel(const unsigned short* __restrict__ Qg,
                            const unsigned short* __restrict__ Kg,
                            const unsigned short* __restrict__ Vt,
                            unsigned short* __restrict__ Og) {
  __shared__ alignas(16) unsigned short k_lds[2][64 * 64];
  __shared__ alignas(16) unsigned short v_lds[2][64 * 64];
  int orig = blockIdx.y * 32 + blockIdx.x;
  int wg = (orig & 7) * 128 + (orig >> 3);
  int qt = wg & 31, bh = wg >> 5;

  int t = threadIdx.x, w = t >> 6, l = t & 63, lr = l & 15, hi = l >> 4;
  const unsigned short* Qh = Qg + (long)bh * 131072;
  const char* Kh = (const char*)(Kg + (long)bh * 131072);
  const char* Vh = (const char*)(Vt + (long)bh * 131072);

  int qrow = qt * 64 + w * 16 + lr;
  bf16x8 qf0 = *(const bf16x8*)(Qh + (long)qrow * 64 + hi * 8);
  bf16x8 qf1 = *(const bf16x8*)(Qh + (long)qrow * 64 + 32 + hi * 8);
  // force the q-load wait outside the k-loop
  asm volatile("" :: "v"(qf0), "v"(qf1));

  const f32x4 z4 = {0.f, 0.f, 0.f, 0.f};
  f32x4 accO[4];
#pragma unroll
  for (int j = 0; j < 4; j++) accO[j] = z4;
  float m_q = -1e30f, lsum = 0.f;

#define STAGE(b, kt)                                                           \
  do {                                                                         \
    _Pragma("unroll")                                                          \
    for (int i = 0; i < 2; i++) {                                              \
      int o = (t + i * 256) * 16;                                              \
      int row = o >> 7;                                                        \
      int colb = (o & 127) ^ ((row & 7) << 4);                                 \
      ASYNC_LD16(Kh + (long)((kt) * 64 + row) * 128 + colb,                    \
                 (char*)k_lds[b] + (w * 64 + i * 256) * 16);                   \
      ASYNC_LD16(Vh + (long)row * 4096 + (kt) * 128 + colb,                    \
                 (char*)v_lds[b] + (w * 64 + i * 256) * 16);                   \
    }                                                                          \
  } while (0)

  STAGE(0, 0);

  for (int kt = 0; kt < 32; ++kt) {
    int cur = kt & 1;
    if (kt < 31) {
      STAGE(cur ^ 1, kt + 1);                       // prefetch next tile
      asm volatile("s_waitcnt vmcnt(4)" ::: "memory");  // cur's 4 loads done
    } else {
      asm volatile("s_waitcnt vmcnt(0)" ::: "memory");
    }
    __builtin_amdgcn_s_barrier();

    // ---- QK^T (swapped operands) ----
    f32x4 sacc[4];
#pragma unroll
    for (int kbk = 0; kbk < 4; kbk++) sacc[kbk] = z4;
    __builtin_amdgcn_s_setprio(1);
#pragma unroll
    for (int kbk = 0; kbk < 4; kbk++) {
      int krow = kbk * 16 + lr;
      int sw = (krow & 7) << 4;
      const char* kbase = (const char*)k_lds[cur] + krow * 128;
      bf16x8 kf0 = *(const bf16x8*)(kbase + ((hi * 16) ^ sw));
      bf16x8 kf1 = *(const bf16x8*)(kbase + ((64 + hi * 16) ^ sw));
      sacc[kbk] = __builtin_amdgcn_mfma_f32_16x16x32_bf16(kf0, qf0, sacc[kbk], 0, 0, 0);
      sacc[kbk] = __builtin_amdgcn_mfma_f32_16x16x32_bf16(kf1, qf1, sacc[kbk], 0, 0, 0);
    }
    __builtin_amdgcn_s_setprio(0);

    // ---- online softmax (exp2 domain), stats per q=lr ----
    float mx = -1e30f;
#pragma unroll
    for (int kbk = 0; kbk < 4; kbk++)
#pragma unroll
      for (int r = 0; r < 4; r++) mx = fmaxf(mx, sacc[kbk][r]);
    mx = fmaxf(mx, __shfl_xor(mx, 16));
    mx = fmaxf(mx, __shfl_xor(mx, 32));
    if (!__all(mx <= m_q + 8.f)) {                  // defer-max (T13)
      float mnew = fmaxf(m_q, mx);
      float fac = exp2f(m_q - mnew);
      m_q = mnew;
      lsum *= fac;
      float fj[4];
#pragma unroll
      for (int j = 0; j < 4; j++) fj[j] = __shfl(fac, ((l >> 4) << 2) | j);
#pragma unroll
      for (int db = 0; db < 4; db++)
#pragma unroll
        for (int j = 0; j < 4; j++) accO[db][j] *= fj[j];
    }
    float rs = 0.f;
#pragma unroll
    for (int kbk = 0; kbk < 4; kbk++)
#pragma unroll
      for (int r = 0; r < 4; r++) {
        float p = exp2f(sacc[kbk][r] - m_q);
        sacc[kbk][r] = p;
        rs += p;
      }
    rs += __shfl_xor(rs, 16);
    rs += __shfl_xor(rs, 32);
    lsum += rs;

    // pack P into PV A-fragments (pure in-lane)
    bf16x8 pa0, pa1;
#pragma unroll
    for (int r = 0; r < 4; r++) {
      pa0[r] = (short)f2bf(sacc[0][r]);
      pa0[r + 4] = (short)f2bf(sacc[1][r]);
      pa1[r] = (short)f2bf(sacc[2][r]);
      pa1[r + 4] = (short)f2bf(sacc[3][r]);
    }

    // ---- PV ----
    __builtin_amdgcn_s_setprio(1);
#pragma unroll
    for (int g = 0; g < 2; g++) {
      bf16x8 pf = g ? pa1 : pa0;
#pragma unroll
      for (int db = 0; db < 4; db++) {
        int d = db * 16 + lr;
        int sw = (d & 7) << 4;
        bf16x8 vf = *(const bf16x8*)((const char*)v_lds[cur] + d * 128 + ((g * 64 + hi * 16) ^ sw));
        accO[db] = __builtin_amdgcn_mfma_f32_16x16x32_bf16(pf, vf, accO[db], 0, 0, 0);
      }
    }
    __builtin_amdgcn_s_setprio(0);

    if (kt < 31) {
      asm volatile("s_waitcnt lgkmcnt(0)" ::: "memory");
      __builtin_amdgcn_s_barrier();                 // cur fully read; next iter overwrites
    }
  }
#undef STAGE

  float linv[4];
#pragma unroll
  for (int j = 0; j < 4; j++) linv[j] = 1.f / __shfl(lsum, ((l >> 4) << 2) | j);

  int b = bh >> 4, h = bh & 15;
#pragma unroll
  for (int db = 0; db < 4; db++)
#pragma unroll
    for (int j = 0; j < 4; j++) {
      int s = qt * 64 + w * 16 + hi * 4 + j;
      Og[((long)(b * 2048 + s)) * 1024 + h * 64 + db * 16 + lr] = f2bf(accO[db][j] * linv[j]);
    }
}

// ---------------- launch ----------------
extern "C" void kernel_launch(void* const* d_in, const int* in_sizes, int n_in,
                              void* d_out, int out_size, void* d_ws, size_t ws_size,
                              hipStream_t stream) {
  const float* x = (const float*)d_in[0];
  const float* w_qkv = (const float*)d_in[1];
  const float* w_hproj = (const float*)d_in[2];
  const float* b_hproj = (const float*)d_in[3];
  const float* w_out = (const float*)d_in[4];
  const float* b_out = (const float*)d_in[5];
  const float* w_fc1 = (const float*)d_in[6];
  const float* b_fc1 = (const float*)d_in[7];
  const float* w_fc2 = (const float*)d_in[8];
  const float* b_fc2 = (const float*)d_in[9];
  const float* g1 = (const float*)d_in[10];
  const float* be1 = (const float*)d_in[11];
  const float* g2 = (const float*)d_in[12];
  const float* be2 = (const float*)d_in[13];
  float* out = (float*)d_out;

  char* ws = (char*)d_ws;
  unsigned short* wqkvt = (unsigned short*)(ws + 0);            // 6291456
  unsigned short* wfc1t = (unsigned short*)(ws + 6291456);      // 8388608
  unsigned short* wfc2t = (unsigned short*)(ws + 14680064);     // 8388608
  unsigned short* wcombt = (unsigned short*)(ws + 23068672);    // 2097152
  float* bcomb = (float*)(ws + 25165824);                       // 4096
  unsigned short* xn = (unsigned short*)(ws + 25169920);        // 8388608
  unsigned short* qb = (unsigned short*)(ws + 33558528);        // 8388608
  unsigned short* kb = (unsigned short*)(ws + 41947136);        // 8388608
  unsigned short* vb = (unsigned short*)(ws + 50335744);        // 8388608
  unsigned short* attn_o = (unsigned short*)(ws + 58724352);    // 8388608
  unsigned short* h1 = qb;
  unsigned short* vt = xn;

  // weight prep
  trans_f32_bf16<<<dim3(3, 16, 16), 256, 0, stream>>>(w_qkv, wqkvt, 1024, 192,
                                                      196608L, 196608L);
  trans_f32_bf16<<<dim3(64, 16, 1), 256, 0, stream>>>(w_fc1, wfc1t, 1024, 4096, 0, 0);
  trans_f32_bf16<<<dim3(16, 64, 1), 256, 0, stream>>>(w_fc2, wfc2t, 4096, 1024, 0, 0);
  combine_wout<<<1024, 256, 0, stream>>>(w_hproj, w_out, wcombt);
  combine_bias<<<32, 256, 0, stream>>>(b_hproj, w_out, b_out, bcomb);

  // MSA branch
  ln_kernel<<<4096, 256, 0, stream>>>(x, g1, be1, xn);
  gemm_bt<EPI_QKV><<<dim3(32, 24), 256, 0, stream>>>(xn, wqkvt, 3072, 1024,
      nullptr, nullptr, nullptr, nullptr, qb, kb, vb);
  transpose_v<<<dim3(32, 32), 256, 0, stream>>>(vb, vt);
  attn_kernel<<<dim3(32, 32), 256, 0, stream>>>(qb, kb, vt, attn_o);
  gemm_bt<EPI_BIASRES><<<dim3(32, 8), 256, 0, stream>>>(attn_o, wcombt, 1024, 1024,
      bcomb, x, out, nullptr, nullptr, nullptr, nullptr);

  // MLP branch
  ln_kernel<<<4096, 256, 0, stream>>>(out, g2, be2, xn);
  gemm_bt<EPI_GELU><<<dim3(32, 32), 256, 0, stream>>>(xn, wfc1t, 4096, 1024,
      b_fc1, nullptr, nullptr, h1, nullptr, nullptr, nullptr);
  gemm_bt<EPI_BIASRES><<<dim3(32, 8), 256, 0, stream>>>(h1, wfc2t, 1024, 4096,
      b_fc2, out, out, nullptr, nullptr, nullptr, nullptr);
}

// Round 4
// 377.973 us; speedup vs baseline: 1.2917x; 1.0007x over previous
//
#include <hip/hip_runtime.h>
#include <hip/hip_bf16.h>
#include <math.h>

#define DEV __device__ __forceinline__

typedef float f32x4 __attribute__((ext_vector_type(4)));
typedef short bf16x8 __attribute__((ext_vector_type(8)));

DEV unsigned short f2bf(float f) {
  union { float f; unsigned int u; } c; c.f = f;
  return (unsigned short)((c.u + 0x7FFF + ((c.u >> 16) & 1)) >> 16);
}

#define ASYNC_LD16(gp, lp)                                                     \
  __builtin_amdgcn_global_load_lds(                                            \
      (const __attribute__((address_space(1))) void*)(gp),                     \
      (__attribute__((address_space(3))) void*)(lp), 16, 0, 0)

// ---------------- weight prep: tiled transpose fp32 -> bf16 ----------------
__global__ void trans_f32_bf16(const float* __restrict__ in, unsigned short* __restrict__ out,
                               int R, int C, long inBatch, long outBatch) {
  __shared__ float tile[64][65];
  int ct = blockIdx.x, rt = blockIdx.y, z = blockIdx.z;
  const float* src = in + (long)z * inBatch + (long)rt * 64 * C + ct * 64;
  unsigned short* dst = out + (long)z * outBatch + (long)ct * 64 * R + rt * 64;
  int t = threadIdx.x, c = t & 63, r0 = t >> 6;
#pragma unroll
  for (int i = 0; i < 16; i++) {
    int r = i * 4 + r0;
    tile[r][c] = src[(long)r * C + c];
  }
  __syncthreads();
#pragma unroll
  for (int i = 0; i < 16; i++) {
    int r = i * 4 + r0;
    dst[(long)r * R + c] = f2bf(tile[c][r]);
  }
}

// W_comb[hd][e] = sum_dp w_hproj[h][d][dp] * w_out[h*64+dp][e]; store Bt
__global__ void combine_wout(const float* __restrict__ w_hproj, const float* __restrict__ w_out,
                             unsigned short* __restrict__ wcombt) {
  int hd = blockIdx.x;
  int h = hd >> 6, d = hd & 63;
  for (int i = 0; i < 4; i++) {
    int e = threadIdx.x + i * 256;
    float acc = 0.f;
    for (int dp = 0; dp < 64; dp++)
      acc += w_hproj[(h * 64 + d) * 64 + dp] * w_out[(h * 64 + dp) * 1024 + e];
    wcombt[(long)e * 1024 + hd] = f2bf(acc);
  }
}

// bcomb[e] = b_out[e] + sum_k b_hproj[k] * w_out[k][e].  grid 32 x 256.
__global__ void combine_bias(const float* __restrict__ b_hproj, const float* __restrict__ w_out,
                             const float* __restrict__ b_out, float* __restrict__ bcomb) {
  __shared__ float part[8][32];
  int e = blockIdx.x * 32 + (threadIdx.x & 31);
  int ks = threadIdx.x >> 5;
  float acc = 0.f;
  for (int k = ks * 128; k < ks * 128 + 128; k++) acc += b_hproj[k] * w_out[(long)k * 1024 + e];
  part[ks][threadIdx.x & 31] = acc;
  __syncthreads();
  if (threadIdx.x < 32) {
    float s = b_out[e];
#pragma unroll
    for (int i = 0; i < 8; i++) s += part[i][threadIdx.x];
    bcomb[e] = s;
  }
}

// V [bh][2048 s][64 d] -> Vt [bh][64 d][2048 s], with key order inside each
// 64-key tile permuted to match the PV MFMA A-fragment slot layout:
// slot p holds key kappa(p) = (2g+sub)*16 + hi*4 + jj  where
// p = g*32 + hi*8 + sub*4 + jj.  (So P needs ZERO cross-lane movement.)
__global__ void transpose_v(const unsigned short* __restrict__ in, unsigned short* __restrict__ out) {
  __shared__ unsigned short tile[64][65];
  int st = blockIdx.x, bh = blockIdx.y;
  const unsigned short* src = in + (long)bh * 131072 + (long)st * 64 * 64;
  unsigned short* dst = out + (long)bh * 131072 + (long)st * 64;
  int t = threadIdx.x, c = t & 63, r0 = t >> 6;
#pragma unroll
  for (int i = 0; i < 16; i++) tile[i * 4 + r0][c] = src[(i * 4 + r0) * 64 + c];
  __syncthreads();
  // position of key c within the 64-tile
  int kb = c >> 4, g = kb >> 1, sub = kb & 1, hi2 = (c >> 2) & 3, jj = c & 3;
  int pos = g * 32 + hi2 * 8 + sub * 4 + jj;
#pragma unroll
  for (int i = 0; i < 16; i++) {
    int d = i * 4 + r0;
    dst[(long)d * 2048 + pos] = tile[c][d];
  }
}

// ---------------- layernorm (fp32 in -> bf16 out) ----------------
__launch_bounds__(256)
__global__ void ln_kernel(const float* __restrict__ x, const float* __restrict__ g,
                          const float* __restrict__ b, unsigned short* __restrict__ out) {
  int row = blockIdx.x, t = threadIdx.x;
  float4 v = ((const float4*)(x + (long)row * 1024))[t];
  float s = v.x + v.y + v.z + v.w;
  float s2 = v.x * v.x + v.y * v.y + v.z * v.z + v.w * v.w;
  for (int o = 32; o; o >>= 1) { s += __shfl_down(s, o); s2 += __shfl_down(s2, o); }
  __shared__ float red[8];
  int w = t >> 6, l = t & 63;
  if (l == 0) { red[w] = s; red[w + 4] = s2; }
  __syncthreads();
  s = red[0] + red[1] + red[2] + red[3];
  s2 = red[4] + red[5] + red[6] + red[7];
  float mu = s * (1.f / 1024.f);
  float var = s2 * (1.f / 1024.f) - mu * mu;
  float rs = rsqrtf(var + 1e-5f);
  float4 gv = ((const float4*)g)[t];
  float4 bv = ((const float4*)b)[t];
  ushort4 o4;
  o4.x = f2bf((v.x - mu) * rs * gv.x + bv.x);
  o4.y = f2bf((v.y - mu) * rs * gv.y + bv.y);
  o4.z = f2bf((v.z - mu) * rs * gv.z + bv.z);
  o4.w = f2bf((v.w - mu) * rs * gv.w + bv.w);
  ((ushort4*)(out + (long)row * 1024))[t] = o4;
}

// ---------------- GEMM: C[M,N] = A[M,K] * Bt[N,K]^T, bf16 MFMA ----------------
#define EPI_QKV 0
#define EPI_BIASRES 1
#define EPI_GELU 2

template <int EPI>
__launch_bounds__(256)
__global__ void gemm_bt(const unsigned short* __restrict__ A, const unsigned short* __restrict__ Bt,
                        int N, int K, const float* __restrict__ bias, const float* resid,
                        float* outf, unsigned short* __restrict__ outb,
                        unsigned short* __restrict__ qb, unsigned short* __restrict__ kb,
                        unsigned short* __restrict__ vb) {
  __shared__ alignas(16) unsigned short lds_a[128 * 64];
  __shared__ alignas(16) unsigned short lds_b[128 * 64];
  int gx = gridDim.x, nwg = gx * gridDim.y;
  int orig = blockIdx.y * gx + blockIdx.x;
  int cpx = nwg >> 3;
  int wg = (orig & 7) * cpx + (orig >> 3);
  int bm = wg % gx, bn = wg / gx;

  int t = threadIdx.x, w = t >> 6, l = t & 63;
  int wm = w >> 1, wn = w & 1;
  int lr = l & 15, lh = l >> 4;

  f32x4 acc[4][4];
  const f32x4 z4 = {0.f, 0.f, 0.f, 0.f};
#pragma unroll
  for (int m = 0; m < 4; m++)
#pragma unroll
    for (int n = 0; n < 4; n++) acc[m][n] = z4;

  int nk = K >> 6;
  for (int kt = 0; kt < nk; ++kt) {
    __syncthreads();
#pragma unroll
    for (int i = 0; i < 4; i++) {
      int e = i * 2048 + w * 512 + l * 8;
      int row = e >> 6, col = e & 63;
      ASYNC_LD16(A + (long)(bm * 128 + row) * K + kt * 64 + col, lds_a + i * 2048 + w * 512);
      ASYNC_LD16(Bt + (long)(bn * 128 + row) * K + kt * 64 + col, lds_b + i * 2048 + w * 512);
    }
    __syncthreads();
#pragma unroll
    for (int kc = 0; kc < 2; kc++) {
      bf16x8 af[4], bfr[4];
#pragma unroll
      for (int m = 0; m < 4; m++)
        af[m] = *(const bf16x8*)&lds_a[(wm * 64 + m * 16 + lr) * 64 + kc * 32 + lh * 8];
#pragma unroll
      for (int n = 0; n < 4; n++)
        bfr[n] = *(const bf16x8*)&lds_b[(wn * 64 + n * 16 + lr) * 64 + kc * 32 + lh * 8];
      __builtin_amdgcn_s_setprio(1);
#pragma unroll
      for (int m = 0; m < 4; m++)
#pragma unroll
        for (int n = 0; n < 4; n++)
          acc[m][n] = __builtin_amdgcn_mfma_f32_16x16x32_bf16(af[m], bfr[n], acc[m][n], 0, 0, 0);
      __builtin_amdgcn_s_setprio(0);
    }
  }

#pragma unroll
  for (int m = 0; m < 4; m++) {
#pragma unroll
    for (int n = 0; n < 4; n++) {
      int c = bn * 128 + wn * 64 + n * 16 + lr;
#pragma unroll
      for (int j = 0; j < 4; j++) {
        int r = bm * 128 + wm * 64 + m * 16 + lh * 4 + j;
        float val = acc[m][n][j];
        if (EPI == EPI_QKV) {
          int h = c / 192, f = c - h * 192;
          int part = f >> 6, d = f & 63;
          int b = r >> 11, s = r & 2047;
          long idx = ((long)(b * 16 + h) * 2048 + s) * 64 + d;
          // q pre-scaled by 1/8 * log2(e) so attention softmax runs in exp2 domain
          if (part == 0) qb[idx] = f2bf(val * 0.18033688011112042f);
          else if (part == 1) kb[idx] = f2bf(val);
          else vb[idx] = f2bf(val);
        } else if (EPI == EPI_BIASRES) {
          long idx = (long)r * N + c;
          outf[idx] = val + bias[c] + resid[idx];
        } else {  // GELU (tanh form; |err| ~3e-3 << 0.1175 threshold, under bf16 quant)
          float u = val + bias[c];
          float z2 = u * (0.7978845608f + 0.0356774081f * u * u) * 2.885390082f;
          float e2 = exp2f(z2);
          float th = 1.f - 2.f / (e2 + 1.f);
          outb[(long)r * N + c] = f2bf(0.5f * u * (1.f + th));
        }
      }
    }
  }
}

// ---------------- flash attention, in-register softmax ----------------
// Swapped QK^T: sacc = mfma(K_frag, Q_frag) -> S^T, lane owns q=lane&15,
// keys kappa = kbk*16 + hi*4 + reg (hi = lane>>4). Row softmax: 15 in-lane
// fmax + 2 shfl_xor. P feeds PV A-frag directly (V pre-permuted in global).
__launch_bounds__(256)
__global__ void attn_kernel(const unsigned short* __restrict__ Qg,
                            const unsigned short* __restrict__ Kg,
                            const unsigned short* __restrict__ Vt,
                            unsigned short* __restrict__ Og) {
  __shared__ alignas(16) unsigned short k_lds[2][64 * 64];
  __shared__ alignas(16) unsigned short v_lds[2][64 * 64];
  int orig = blockIdx.y * 32 + blockIdx.x;
  int wg = (orig & 7) * 128 + (orig >> 3);
  int qt = wg & 31, bh = wg >> 5;

  int t = threadIdx.x, w = t >> 6, l = t & 63, lr = l & 15, hi = l >> 4;
  const unsigned short* Qh = Qg + (long)bh * 131072;
  const char* Kh = (const char*)(Kg + (long)bh * 131072);
  const char* Vh = (const char*)(Vt + (long)bh * 131072);

  int qrow = qt * 64 + w * 16 + lr;
  bf16x8 qf0 = *(const bf16x8*)(Qh + (long)qrow * 64 + hi * 8);
  bf16x8 qf1 = *(const bf16x8*)(Qh + (long)qrow * 64 + 32 + hi * 8);
  // force the q-load wait outside the k-loop
  asm volatile("" :: "v"(qf0), "v"(qf1));

  const f32x4 z4 = {0.f, 0.f, 0.f, 0.f};
  f32x4 accO[4];
#pragma unroll
  for (int j = 0; j < 4; j++) accO[j] = z4;
  float m_q = -1e30f, lsum = 0.f;

#define STAGE(b, kt)                                                           \
  do {                                                                         \
    _Pragma("unroll")                                                          \
    for (int i = 0; i < 2; i++) {                                              \
      int o = (t + i * 256) * 16;                                              \
      int row = o >> 7;                                                        \
      int colb = (o & 127) ^ ((row & 7) << 4);                                 \
      ASYNC_LD16(Kh + (long)((kt) * 64 + row) * 128 + colb,                    \
                 (char*)k_lds[b] + (w * 64 + i * 256) * 16);                   \
      ASYNC_LD16(Vh + (long)row * 4096 + (kt) * 128 + colb,                    \
                 (char*)v_lds[b] + (w * 64 + i * 256) * 16);                   \
    }                                                                          \
  } while (0)

  STAGE(0, 0);

  for (int kt = 0; kt < 32; ++kt) {
    int cur = kt & 1;
    if (kt < 31) {
      STAGE(cur ^ 1, kt + 1);                       // prefetch next tile
      asm volatile("s_waitcnt vmcnt(4)" ::: "memory");  // cur's 4 loads done
    } else {
      asm volatile("s_waitcnt vmcnt(0)" ::: "memory");
    }
    __builtin_amdgcn_s_barrier();

    // ---- QK^T (swapped operands) ----
    f32x4 sacc[4];
#pragma unroll
    for (int kbk = 0; kbk < 4; kbk++) sacc[kbk] = z4;
    __builtin_amdgcn_s_setprio(1);
#pragma unroll
    for (int kbk = 0; kbk < 4; kbk++) {
      int krow = kbk * 16 + lr;
      int sw = (krow & 7) << 4;
      const char* kbase = (const char*)k_lds[cur] + krow * 128;
      bf16x8 kf0 = *(const bf16x8*)(kbase + ((hi * 16) ^ sw));
      bf16x8 kf1 = *(const bf16x8*)(kbase + ((64 + hi * 16) ^ sw));
      sacc[kbk] = __builtin_amdgcn_mfma_f32_16x16x32_bf16(kf0, qf0, sacc[kbk], 0, 0, 0);
      sacc[kbk] = __builtin_amdgcn_mfma_f32_16x16x32_bf16(kf1, qf1, sacc[kbk], 0, 0, 0);
    }
    __builtin_amdgcn_s_setprio(0);

    // ---- online softmax (exp2 domain), stats per q=lr ----
    float mx = -1e30f;
#pragma unroll
    for (int kbk = 0; kbk < 4; kbk++)
#pragma unroll
      for (int r = 0; r < 4; r++) mx = fmaxf(mx, sacc[kbk][r]);
    mx = fmaxf(mx, __shfl_xor(mx, 16));
    mx = fmaxf(mx, __shfl_xor(mx, 32));
    if (!__all(mx <= m_q + 8.f)) {                  // defer-max (T13)
      float mnew = fmaxf(m_q, mx);
      float fac = exp2f(m_q - mnew);
      m_q = mnew;
      lsum *= fac;
      float fj[4];
#pragma unroll
      for (int j = 0; j < 4; j++) fj[j] = __shfl(fac, ((l >> 4) << 2) | j);
#pragma unroll
      for (int db = 0; db < 4; db++)
#pragma unroll
        for (int j = 0; j < 4; j++) accO[db][j] *= fj[j];
    }
    float rs = 0.f;
#pragma unroll
    for (int kbk = 0; kbk < 4; kbk++)
#pragma unroll
      for (int r = 0; r < 4; r++) {
        float p = exp2f(sacc[kbk][r] - m_q);
        sacc[kbk][r] = p;
        rs += p;
      }
    rs += __shfl_xor(rs, 16);
    rs += __shfl_xor(rs, 32);
    lsum += rs;

    // pack P into PV A-fragments (pure in-lane)
    bf16x8 pa0, pa1;
#pragma unroll
    for (int r = 0; r < 4; r++) {
      pa0[r] = (short)f2bf(sacc[0][r]);
      pa0[r + 4] = (short)f2bf(sacc[1][r]);
      pa1[r] = (short)f2bf(sacc[2][r]);
      pa1[r + 4] = (short)f2bf(sacc[3][r]);
    }

    // ---- PV ----
    __builtin_amdgcn_s_setprio(1);
#pragma unroll
    for (int g = 0; g < 2; g++) {
      bf16x8 pf = g ? pa1 : pa0;
#pragma unroll
      for (int db = 0; db < 4; db++) {
        int d = db * 16 + lr;
        int sw = (d & 7) << 4;
        bf16x8 vf = *(const bf16x8*)((const char*)v_lds[cur] + d * 128 + ((g * 64 + hi * 16) ^ sw));
        accO[db] = __builtin_amdgcn_mfma_f32_16x16x32_bf16(pf, vf, accO[db], 0, 0, 0);
      }
    }
    __builtin_amdgcn_s_setprio(0);

    if (kt < 31) {
      asm volatile("s_waitcnt lgkmcnt(0)" ::: "memory");
      __builtin_amdgcn_s_barrier();                 // cur fully read; next iter overwrites
    }
  }
#undef STAGE

  float linv[4];
#pragma unroll
  for (int j = 0; j < 4; j++) linv[j] = 1.f / __shfl(lsum, ((l >> 4) << 2) | j);

  int b = bh >> 4, h = bh & 15;
#pragma unroll
  for (int db = 0; db < 4; db++)
#pragma unroll
    for (int j = 0; j < 4; j++) {
      int s = qt * 64 + w * 16 + hi * 4 + j;
      Og[((long)(b * 2048 + s)) * 1024 + h * 64 + db * 16 + lr] = f2bf(accO[db][j] * linv[j]);
    }
}

// ---------------- launch ----------------
extern "C" void kernel_launch(void* const* d_in, const int* in_sizes, int n_in,
                              void* d_out, int out_size, void* d_ws, size_t ws_size,
                              hipStream_t stream) {
  const float* x = (const float*)d_in[0];
  const float* w_qkv = (const float*)d_in[1];
  const float* w_hproj = (const float*)d_in[2];
  const float* b_hproj = (const float*)d_in[3];
  const float* w_out = (const float*)d_in[4];
  const float* b_out = (const float*)d_in[5];
  const float* w_fc1 = (const float*)d_in[6];
  const float* b_fc1 = (const float*)d_in[7];
  const float* w_fc2 = (const float*)d_in[8];
  const float* b_fc2 = (const float*)d_in[9];
  const float* g1 = (const float*)d_in[10];
  const float* be1 = (const float*)d_in[11];
  const float* g2 = (const float*)d_in[12];
  const float* be2 = (const float*)d_in[13];
  float* out = (float*)d_out;

  char* ws = (char*)d_ws;
  unsigned short* wqkvt = (unsigned short*)(ws + 0);            // 6291456
  unsigned short* wfc1t = (unsigned short*)(ws + 6291456);      // 8388608
  unsigned short* wfc2t = (unsigned short*)(ws + 14680064);     // 8388608
  unsigned short* wcombt = (unsigned short*)(ws + 23068672);    // 2097152
  float* bcomb = (float*)(ws + 25165824);                       // 4096
  unsigned short* xn = (unsigned short*)(ws + 25169920);        // 8388608
  unsigned short* qb = (unsigned short*)(ws + 33558528);        // 8388608
  unsigned short* kb = (unsigned short*)(ws + 41947136);        // 8388608
  unsigned short* vb = (unsigned short*)(ws + 50335744);        // 8388608
  unsigned short* attn_o = (unsigned short*)(ws + 58724352);    // 8388608
  unsigned short* h1 = qb;
  unsigned short* vt = xn;

  // weight prep
  trans_f32_bf16<<<dim3(3, 16, 16), 256, 0, stream>>>(w_qkv, wqkvt, 1024, 192,
                                                      196608L, 196608L);
  trans_f32_bf16<<<dim3(64, 16, 1), 256, 0, stream>>>(w_fc1, wfc1t, 1024, 4096, 0, 0);
  trans_f32_bf16<<<dim3(16, 64, 1), 256, 0, stream>>>(w_fc2, wfc2t, 4096, 1024, 0, 0);
  combine_wout<<<1024, 256, 0, stream>>>(w_hproj, w_out, wcombt);
  combine_bias<<<32, 256, 0, stream>>>(b_hproj, w_out, b_out, bcomb);

  // MSA branch
  ln_kernel<<<4096, 256, 0, stream>>>(x, g1, be1, xn);
  gemm_bt<EPI_QKV><<<dim3(32, 24), 256, 0, stream>>>(xn, wqkvt, 3072, 1024,
      nullptr, nullptr, nullptr, nullptr, qb, kb, vb);
  transpose_v<<<dim3(32, 32), 256, 0, stream>>>(vb, vt);
  attn_kernel<<<dim3(32, 32), 256, 0, stream>>>(qb, kb, vt, attn_o);
  gemm_bt<EPI_BIASRES><<<dim3(32, 8), 256, 0, stream>>>(attn_o, wcombt, 1024, 1024,
      bcomb, x, out, nullptr, nullptr, nullptr, nullptr);

  // MLP branch
  ln_kernel<<<4096, 256, 0, stream>>>(out, g2, be2, xn);
  gemm_bt<EPI_GELU><<<dim3(32, 32), 256, 0, stream>>>(xn, wfc1t, 4096, 1024,
      b_fc1, nullptr, nullptr, h1, nullptr, nullptr, nullptr);
  gemm_bt<EPI_BIASRES><<<dim3(32, 8), 256, 0, stream>>>(h1, wfc2t, 1024, 4096,
      b_fc2, out, out, nullptr, nullptr, nullptr, nullptr);
}